// Round 1
// baseline (1582.084 us; speedup 1.0000x reference)
//
#include <hip/hip_runtime.h>

// Problem constants (fixed by reference: H=W=256, B=2, FLOW_SCALING=256, MAX_TS=1)
#define HH 256
#define WW 256
#define HW (HH * WW)
#define BATCH 2
#define NPASS 2
#define EPSF 1e-9f
#define FLOW_SCALE 256.0f

// ws layout (floats):
//   hist:    [pass][b][4][HW]   4 slices = {iwe_pos, iwe_neg, ts_pos, ts_neg}
//            total NPASS*BATCH*4*HW = 16*65536 floats = 4 MiB
//   partial: loss[4], nz[4]  at offset 16*HW
#define HIST_FLOATS (NPASS * BATCH * 4 * HW)

__global__ __launch_bounds__(256) void ew_scatter(
    const float4* __restrict__ events,   // [B,N] of (ts,x,y,p)
    const float2* __restrict__ flow,     // [B,N] of (fx,fy)
    float* __restrict__ hist, int N) {
  const int b = blockIdx.y;
  events += (size_t)b * N;
  flow += (size_t)b * N;
  float* __restrict__ hb = hist + (size_t)b * 4 * HW;  // batch offset inside each pass block

  for (int i = blockIdx.x * blockDim.x + threadIdx.x; i < N;
       i += gridDim.x * blockDim.x) {
    const float4 e = events[i];
    const float2 f = flow[i];
    const float ts = e.x, x = e.y, y = e.z, p = e.w;
    const int polofs = (p > 0.0f) ? 0 : HW;  // pos hist first, then neg

#pragma unroll
    for (int pass = 0; pass < NPASS; ++pass) {
      const float tref = (pass == 0) ? 1.0f : 0.0f;
      const float dt = tref - ts;
      const float wx = fmaf(dt * f.x, FLOW_SCALE, x);
      const float wy = fmaf(dt * f.y, FLOW_SCALE, y);
      const float lxf = floorf(wx);
      const float tyf = floorf(wy);
      const float fx = wx - lxf;  // [0,1)
      const float fy = wy - tyf;
      const int lx = (int)lxf;
      const int ty = (int)tyf;

      float* __restrict__ wbase =
          hb + (size_t)pass * BATCH * 4 * HW + polofs;   // weight hist
      float* __restrict__ tbase = wbase + 2 * HW;        // ts-weight hist

      const float w00 = (1.0f - fx) * (1.0f - fy);
      const float w10 = fx * (1.0f - fy);
      const float w01 = (1.0f - fx) * fy;
      const float w11 = fx * fy;

      const int cx0 = lx, cx1 = lx + 1, cy0 = ty, cy1 = ty + 1;
      const bool inx0 = (cx0 >= 0) & (cx0 < WW);
      const bool inx1 = (cx1 >= 0) & (cx1 < WW);
      const bool iny0 = (cy0 >= 0) & (cy0 < HH);
      const bool iny1 = (cy1 >= 0) & (cy1 < HH);

      if (inx0 & iny0) {
        const int pix = cy0 * WW + cx0;
        atomicAdd(wbase + pix, w00);
        atomicAdd(tbase + pix, w00 * ts);
      }
      if (inx1 & iny0) {
        const int pix = cy0 * WW + cx1;
        atomicAdd(wbase + pix, w10);
        atomicAdd(tbase + pix, w10 * ts);
      }
      if (inx0 & iny1) {
        const int pix = cy1 * WW + cx0;
        atomicAdd(wbase + pix, w01);
        atomicAdd(tbase + pix, w01 * ts);
      }
      if (inx1 & iny1) {
        const int pix = cy1 * WW + cx1;
        atomicAdd(wbase + pix, w11);
        atomicAdd(tbase + pix, w11 * ts);
      }
    }
  }
}

// One block per (pass, batch): reduce 4*HW histogram floats to loss + nz.
__global__ __launch_bounds__(256) void ew_reduce(const float* __restrict__ hist,
                                                 float* __restrict__ partial) {
  const int g = blockIdx.x;  // pass*BATCH + b, 0..3
  const float* __restrict__ base = hist + (size_t)g * 4 * HW;

  double loss = 0.0;
  double nz = 0.0;
  for (int pix = threadIdx.x; pix < HW; pix += blockDim.x) {
    const float ip = base[pix];
    const float in_ = base[HW + pix];
    const float tp = base[2 * HW + pix];
    const float tn = base[3 * HW + pix];
    const float a = tp / (ip + EPSF);
    const float c = tn / (in_ + EPSF);
    loss += (double)(a * a) + (double)(c * c);
    if ((ip + in_) > 0.0f) nz += 1.0;
  }

  // wave reduce (64 lanes)
  for (int off = 32; off > 0; off >>= 1) {
    loss += __shfl_down(loss, off, 64);
    nz += __shfl_down(nz, off, 64);
  }
  __shared__ double sl[4], sn[4];
  const int wid = threadIdx.x >> 6;
  const int lane = threadIdx.x & 63;
  if (lane == 0) {
    sl[wid] = loss;
    sn[wid] = nz;
  }
  __syncthreads();
  if (threadIdx.x == 0) {
    double L = sl[0] + sl[1] + sl[2] + sl[3];
    double Z = sn[0] + sn[1] + sn[2] + sn[3];
    partial[g] = (float)L;
    partial[4 + g] = (float)Z;
  }
}

__global__ void ew_final(const float* __restrict__ partial,
                         float* __restrict__ out) {
  if (threadIdx.x == 0 && blockIdx.x == 0) {
    float s = 0.0f;
    for (int g = 0; g < NPASS * BATCH; ++g) s += partial[g] / partial[4 + g];
    out[0] = s;
  }
}

extern "C" void kernel_launch(void* const* d_in, const int* in_sizes, int n_in,
                              void* d_out, int out_size, void* d_ws,
                              size_t ws_size, hipStream_t stream) {
  const float4* events = (const float4*)d_in[0];  // [B,N,4]
  const float2* flow = (const float2*)d_in[1];    // [B,N,2]
  float* out = (float*)d_out;
  float* hist = (float*)d_ws;
  float* partial = hist + HIST_FLOATS;

  const int N = in_sizes[0] / (4 * BATCH);  // events per batch

  // zero histograms (partial is fully overwritten by ew_reduce)
  hipMemsetAsync(hist, 0, (size_t)HIST_FLOATS * sizeof(float), stream);

  dim3 sgrid(1024, BATCH);
  ew_scatter<<<sgrid, 256, 0, stream>>>(events, flow, hist, N);
  ew_reduce<<<NPASS * BATCH, 256, 0, stream>>>(hist, partial);
  ew_final<<<1, 64, 0, stream>>>(partial, out);
}

// Round 2
// 311.523 us; speedup vs baseline: 5.0785x; 5.0785x over previous
//
#include <hip/hip_runtime.h>

// Problem constants (fixed by reference: H=W=256, B=2, FLOW_SCALING=256, MAX_TS=1)
#define HH 256
#define WW 256
#define HW (HH * WW)
#define BATCH 2
#define NPASS 2
#define EPSF 1e-9f
#define FLOW_SCALE 256.0f

// ---------------- Fast path: LDS tile privatization ----------------
// Grid: (chunk C=8, tile T=16, pass*2+b = 4). Each block owns a 64x64 tile
// for one (pass,b), streams its event chunk, LDS-accumulates 4 slices
// {pos_w, neg_w, pos_ts, neg_ts}, flushes non-atomically to replica[chunk].
// ws layout (floats):
//   rep:     [C][pb(4)][slice(4)][HW]   C*16*HW floats = 32 MiB (C=8)
//   partial: loss[4][32] then nz[4][32] = 256 floats
#define CHUNKS 8
#define TILES 16
#define TILE_W 64
#define TILE_H 64
#define TILE_PX (TILE_W * TILE_H)
#define REP_FLOATS (CHUNKS * 16 * HW)

__global__ __launch_bounds__(256) void ew_tile(
    const float4* __restrict__ events,  // [B,N] (ts,x,y,p)
    const float2* __restrict__ flow,    // [B,N] (fx,fy)
    float* __restrict__ rep, int N) {
  const int c = blockIdx.x;
  const int tile = blockIdx.y;
  const int pb = blockIdx.z;  // pass*2 + b
  const int b = pb & 1;
  const float tref = (pb >> 1) == 0 ? 1.0f : 0.0f;
  const int tx0 = (tile & 3) * TILE_W;
  const int ty0 = (tile >> 2) * TILE_H;

  __shared__ float lds[4 * TILE_PX];  // 64 KiB exactly
  for (int j = threadIdx.x; j < 4 * TILE_PX; j += 256) lds[j] = 0.0f;
  __syncthreads();

  events += (size_t)b * N;
  flow += (size_t)b * N;
  const int Nc = (N + CHUNKS - 1) / CHUNKS;
  const int i0 = c * Nc;
  const int i1 = (i0 + Nc < N) ? (i0 + Nc) : N;

  for (int i = i0 + threadIdx.x; i < i1; i += 256) {
    const float4 e = events[i];
    const float2 f = flow[i];
    const float ts = e.x;
    const int pol = (e.w > 0.0f) ? 0 : 1;
    const float dt = tref - ts;
    const float wx = fmaf(dt * f.x, FLOW_SCALE, e.y);
    const float wy = fmaf(dt * f.y, FLOW_SCALE, e.z);
    const float lxf = floorf(wx);
    const float tyf = floorf(wy);
    const float fx = wx - lxf;
    const float fy = wy - tyf;
    const int lx = (int)lxf - tx0;  // tile-local
    const int ty = (int)tyf - ty0;
    const float wxs[2] = {1.0f - fx, fx};
    const float wys[2] = {1.0f - fy, fy};
#pragma unroll
    for (int dy = 0; dy < 2; ++dy) {
      const int cy = ty + dy;
      if ((unsigned)cy >= (unsigned)TILE_H) continue;
#pragma unroll
      for (int dx = 0; dx < 2; ++dx) {
        const int cx = lx + dx;
        if ((unsigned)cx >= (unsigned)TILE_W) continue;
        const float w = wxs[dx] * wys[dy];
        const int li = cy * TILE_W + cx;
        atomicAdd(&lds[pol * TILE_PX + li], w);
        atomicAdd(&lds[(pol + 2) * TILE_PX + li], w * ts);
      }
    }
  }
  __syncthreads();

  // non-atomic flush of the whole tile into replica c
  float* __restrict__ dst = rep + ((size_t)c * 16 + (size_t)pb * 4) * HW;
  for (int j = threadIdx.x; j < 4 * TILE_PX; j += 256) {
    const int slice = j >> 12;          // /4096
    const int within = j & (TILE_PX - 1);
    const int row = within >> 6;        // /64
    const int col = within & 63;
    dst[(size_t)slice * HW + (ty0 + row) * WW + tx0 + col] = lds[j];
  }
}

// grid (32, 4): each block reduces 2048 pixels of one (pass,b), summing replicas.
__global__ __launch_bounds__(256) void ew_reduce2(const float* __restrict__ rep,
                                                  float* __restrict__ partial) {
  const int sub = blockIdx.x;  // 0..31
  const int pb = blockIdx.y;   // 0..3
  float loss = 0.0f, nz = 0.0f;
  for (int k = threadIdx.x; k < 2048; k += 256) {
    const int pix = sub * 2048 + k;
    float ip = 0.0f, in_ = 0.0f, tp = 0.0f, tn = 0.0f;
#pragma unroll
    for (int c = 0; c < CHUNKS; ++c) {
      const float* __restrict__ rb =
          rep + ((size_t)c * 16 + (size_t)pb * 4) * HW + pix;
      ip += rb[0];
      in_ += rb[HW];
      tp += rb[2 * HW];
      tn += rb[3 * HW];
    }
    const float a = tp / (ip + EPSF);
    const float d = tn / (in_ + EPSF);
    loss += a * a + d * d;
    nz += ((ip + in_) > 0.0f) ? 1.0f : 0.0f;
  }
  // block reduce (4 waves of 64)
  for (int off = 32; off > 0; off >>= 1) {
    loss += __shfl_down(loss, off, 64);
    nz += __shfl_down(nz, off, 64);
  }
  __shared__ float sl[4], sn[4];
  const int wid = threadIdx.x >> 6;
  if ((threadIdx.x & 63) == 0) {
    sl[wid] = loss;
    sn[wid] = nz;
  }
  __syncthreads();
  if (threadIdx.x == 0) {
    partial[pb * 32 + sub] = sl[0] + sl[1] + sl[2] + sl[3];
    partial[128 + pb * 32 + sub] = sn[0] + sn[1] + sn[2] + sn[3];
  }
}

__global__ void ew_final2(const float* __restrict__ partial,
                          float* __restrict__ out) {
  if (threadIdx.x == 0 && blockIdx.x == 0) {
    float s = 0.0f;
    for (int pb = 0; pb < 4; ++pb) {
      float L = 0.0f, Z = 0.0f;
      for (int j = 0; j < 32; ++j) {
        L += partial[pb * 32 + j];
        Z += partial[128 + pb * 32 + j];
      }
      s += L / Z;
    }
    out[0] = s;
  }
}

// ---------------- Fallback path (round-1 verified): global atomics ----------------
#define HIST_FLOATS (NPASS * BATCH * 4 * HW)

__global__ __launch_bounds__(256) void ew_scatter(
    const float4* __restrict__ events, const float2* __restrict__ flow,
    float* __restrict__ hist, int N) {
  const int b = blockIdx.y;
  events += (size_t)b * N;
  flow += (size_t)b * N;
  float* __restrict__ hb = hist + (size_t)b * 4 * HW;
  for (int i = blockIdx.x * blockDim.x + threadIdx.x; i < N;
       i += gridDim.x * blockDim.x) {
    const float4 e = events[i];
    const float2 f = flow[i];
    const float ts = e.x, x = e.y, y = e.z, p = e.w;
    const int polofs = (p > 0.0f) ? 0 : HW;
#pragma unroll
    for (int pass = 0; pass < NPASS; ++pass) {
      const float tref = (pass == 0) ? 1.0f : 0.0f;
      const float dt = tref - ts;
      const float wx = fmaf(dt * f.x, FLOW_SCALE, x);
      const float wy = fmaf(dt * f.y, FLOW_SCALE, y);
      const float lxf = floorf(wx), tyf = floorf(wy);
      const float fx = wx - lxf, fy = wy - tyf;
      const int lx = (int)lxf, ty = (int)tyf;
      float* __restrict__ wbase = hb + (size_t)pass * BATCH * 4 * HW + polofs;
      float* __restrict__ tbase = wbase + 2 * HW;
      const float w00 = (1.0f - fx) * (1.0f - fy);
      const float w10 = fx * (1.0f - fy);
      const float w01 = (1.0f - fx) * fy;
      const float w11 = fx * fy;
      const int cx0 = lx, cx1 = lx + 1, cy0 = ty, cy1 = ty + 1;
      const bool inx0 = (cx0 >= 0) & (cx0 < WW);
      const bool inx1 = (cx1 >= 0) & (cx1 < WW);
      const bool iny0 = (cy0 >= 0) & (cy0 < HH);
      const bool iny1 = (cy1 >= 0) & (cy1 < HH);
      if (inx0 & iny0) {
        const int pix = cy0 * WW + cx0;
        atomicAdd(wbase + pix, w00);
        atomicAdd(tbase + pix, w00 * ts);
      }
      if (inx1 & iny0) {
        const int pix = cy0 * WW + cx1;
        atomicAdd(wbase + pix, w10);
        atomicAdd(tbase + pix, w10 * ts);
      }
      if (inx0 & iny1) {
        const int pix = cy1 * WW + cx0;
        atomicAdd(wbase + pix, w01);
        atomicAdd(tbase + pix, w01 * ts);
      }
      if (inx1 & iny1) {
        const int pix = cy1 * WW + cx1;
        atomicAdd(wbase + pix, w11);
        atomicAdd(tbase + pix, w11 * ts);
      }
    }
  }
}

__global__ __launch_bounds__(256) void ew_reduce(const float* __restrict__ hist,
                                                 float* __restrict__ partial) {
  const int g = blockIdx.x;
  const float* __restrict__ base = hist + (size_t)g * 4 * HW;
  double loss = 0.0, nz = 0.0;
  for (int pix = threadIdx.x; pix < HW; pix += blockDim.x) {
    const float ip = base[pix];
    const float in_ = base[HW + pix];
    const float tp = base[2 * HW + pix];
    const float tn = base[3 * HW + pix];
    const float a = tp / (ip + EPSF);
    const float c = tn / (in_ + EPSF);
    loss += (double)(a * a) + (double)(c * c);
    if ((ip + in_) > 0.0f) nz += 1.0;
  }
  for (int off = 32; off > 0; off >>= 1) {
    loss += __shfl_down(loss, off, 64);
    nz += __shfl_down(nz, off, 64);
  }
  __shared__ double sl[4], sn[4];
  const int wid = threadIdx.x >> 6;
  if ((threadIdx.x & 63) == 0) {
    sl[wid] = loss;
    sn[wid] = nz;
  }
  __syncthreads();
  if (threadIdx.x == 0) {
    partial[g] = (float)(sl[0] + sl[1] + sl[2] + sl[3]);
    partial[4 + g] = (float)(sn[0] + sn[1] + sn[2] + sn[3]);
  }
}

__global__ void ew_final(const float* __restrict__ partial,
                         float* __restrict__ out) {
  if (threadIdx.x == 0 && blockIdx.x == 0) {
    float s = 0.0f;
    for (int g = 0; g < NPASS * BATCH; ++g) s += partial[g] / partial[4 + g];
    out[0] = s;
  }
}

extern "C" void kernel_launch(void* const* d_in, const int* in_sizes, int n_in,
                              void* d_out, int out_size, void* d_ws,
                              size_t ws_size, hipStream_t stream) {
  const float4* events = (const float4*)d_in[0];
  const float2* flow = (const float2*)d_in[1];
  float* out = (float*)d_out;
  const int N = in_sizes[0] / (4 * BATCH);

  const size_t need_fast = ((size_t)REP_FLOATS + 256) * sizeof(float);
  if (ws_size >= need_fast) {
    float* rep = (float*)d_ws;
    float* partial = rep + REP_FLOATS;
    dim3 tgrid(CHUNKS, TILES, NPASS * BATCH);
    ew_tile<<<tgrid, 256, 0, stream>>>(events, flow, rep, N);
    dim3 rgrid(32, 4);
    ew_reduce2<<<rgrid, 256, 0, stream>>>(rep, partial);
    ew_final2<<<1, 64, 0, stream>>>(partial, out);
  } else {
    float* hist = (float*)d_ws;
    float* partial = hist + HIST_FLOATS;
    hipMemsetAsync(hist, 0, (size_t)HIST_FLOATS * sizeof(float), stream);
    dim3 sgrid(1024, BATCH);
    ew_scatter<<<sgrid, 256, 0, stream>>>(events, flow, hist, N);
    ew_reduce<<<NPASS * BATCH, 256, 0, stream>>>(hist, partial);
    ew_final<<<1, 64, 0, stream>>>(partial, out);
  }
}